// Round 4
// baseline (115.255 us; speedup 1.0000x reference)
//
#include <hip/hip_runtime.h>
#include <hip/hip_bf16.h>
#include <math.h>

#define B 64
#define L 64
#define NPT 127
#define D 128
#define VOCAB 30000
#define LABELS 30
#define SPLIT 4
#define KP 129    // padded LDS row stride (floats) for K/V tiles in k2
#define EP 132    // padded row stride for tree/e tiles (128+4)

typedef __attribute__((ext_vector_type(4))) unsigned int uint4v;

__device__ __forceinline__ float bfhi(unsigned int u) {
  unsigned int x = u & 0xffff0000u;
  return __builtin_bit_cast(float, x);
}
__device__ __forceinline__ float bflo(unsigned int u) {
  unsigned int x = u << 16;
  return __builtin_bit_cast(float, x);
}

// ---------------------------------------------------------------------------
// K0: T[v][e] = bf16( sum_d emb[v][d] * Wc[d][e] + bc[e] )   (bc folded in)
// ---------------------------------------------------------------------------
__global__ __launch_bounds__(256) void k0_embWc(const float* __restrict__ emb,
                                                const float* __restrict__ Wc,
                                                const float* __restrict__ bc,
                                                __hip_bfloat16* __restrict__ T) {
  __shared__ float sW[D * D];  // 64 KB
  const int t = threadIdx.x;
  const int row0 = blockIdx.x * 32;
  {
    const float4* W4 = (const float4*)Wc;
    float4* sW4 = (float4*)sW;
#pragma unroll
    for (int i = 0; i < 16; ++i) sW4[t + 256 * i] = W4[t + 256 * i];
  }
  __syncthreads();
  const int rg = t >> 5;   // 0..7
  const int cg = t & 31;   // 0..31
  const int c0 = cg * 4;
  int rr[4];
#pragma unroll
  for (int i = 0; i < 4; ++i) {
    int g = row0 + rg * 4 + i;
    rr[i] = g < VOCAB ? g : VOCAB - 1;
  }
  const float4* e0 = (const float4*)(emb + (size_t)rr[0] * D);
  const float4* e1 = (const float4*)(emb + (size_t)rr[1] * D);
  const float4* e2 = (const float4*)(emb + (size_t)rr[2] * D);
  const float4* e3 = (const float4*)(emb + (size_t)rr[3] * D);
  const float4* sW4 = (const float4*)sW;
  float4 bcv = *(const float4*)&bc[c0];
  float acc[4][4];
#pragma unroll
  for (int i = 0; i < 4; ++i) {
    acc[i][0] = bcv.x; acc[i][1] = bcv.y; acc[i][2] = bcv.z; acc[i][3] = bcv.w;
  }
#pragma unroll 4
  for (int k4 = 0; k4 < 32; ++k4) {
    float4 a0 = e0[k4], a1 = e1[k4], a2 = e2[k4], a3 = e3[k4];
    const float av0[4] = {a0.x, a0.y, a0.z, a0.w};
    const float av1[4] = {a1.x, a1.y, a1.z, a1.w};
    const float av2[4] = {a2.x, a2.y, a2.z, a2.w};
    const float av3[4] = {a3.x, a3.y, a3.z, a3.w};
#pragma unroll
    for (int j = 0; j < 4; ++j) {
      float4 w = sW4[(k4 * 4 + j) * 32 + cg];
      float b0 = av0[j], b1 = av1[j], b2 = av2[j], b3 = av3[j];
      acc[0][0] += b0 * w.x; acc[0][1] += b0 * w.y; acc[0][2] += b0 * w.z; acc[0][3] += b0 * w.w;
      acc[1][0] += b1 * w.x; acc[1][1] += b1 * w.y; acc[1][2] += b1 * w.z; acc[1][3] += b1 * w.w;
      acc[2][0] += b2 * w.x; acc[2][1] += b2 * w.y; acc[2][2] += b2 * w.z; acc[2][3] += b2 * w.w;
      acc[3][0] += b3 * w.x; acc[3][1] += b3 * w.y; acc[3][2] += b3 * w.z; acc[3][3] += b3 * w.w;
    }
  }
  union BF4 { ushort4 u; unsigned short s[4]; };
#pragma unroll
  for (int i = 0; i < 4; ++i) {
    int g = row0 + rg * 4 + i;
    if (g < VOCAB) {
      BF4 o;
#pragma unroll
      for (int j = 0; j < 4; ++j) {
        __hip_bfloat16 h = __float2bfloat16(acc[i][j]);
        o.s[j] = *(unsigned short*)&h;
      }
      *(ushort4*)&T[(size_t)g * D + c0] = o.u;
    }
  }
}

// ---------------------------------------------------------------------------
// K1a: tree-encode one (b,l) row per block, 512 threads, ALL waves busy.
// Phase 1: transposed gather -> e[127][EP] f32 in LDS.
// Phase 2: level-by-level parallel tree accumulation in LDS.
// Phase 3: per-dim max over 127 nodes, relu -> enc.
// ---------------------------------------------------------------------------
__global__ __launch_bounds__(512) void k1a_tree(
    const int* __restrict__ tokens, const __hip_bfloat16* __restrict__ T,
    float* __restrict__ enc) {
  __shared__ float e[127 * EP];   // ~67 KB
  __shared__ float pmax[4][D];
  __shared__ int stok[128];
  const int t = threadIdx.x;
  const int row = blockIdx.x;
  if (t < 128) stok[t] = (t < NPT) ? tokens[(size_t)row * NPT + t] : 0;
  __syncthreads();
  const int nd = t >> 4;    // 0..31
  const int sub = t & 15;   // 16B chunk
#pragma unroll
  for (int p = 0; p < 4; ++p) {
    const int node = p * 32 + nd;
    if (node < NPT) {
      const int tok = stok[node];
      uint4v v = *(const uint4v*)(T + (size_t)tok * D + sub * 8);
      float* ep = &e[node * EP + sub * 8];
      float4 lo = make_float4(bflo(v.x), bfhi(v.x), bflo(v.y), bfhi(v.y));
      float4 hi = make_float4(bflo(v.z), bfhi(v.z), bflo(v.w), bfhi(v.w));
      *(float4*)ep = lo;
      *(float4*)(ep + 4) = hi;
    }
  }
  __syncthreads();
  // levels 5..0: h[n] += h[2n+1] + h[2n+2]
#pragma unroll
  for (int l = 5; l >= 0; --l) {
    const int start = (1 << l) - 1;
    const int cnt = 1 << l;
    const int elems = cnt * D;
    for (int idx = t; idx < elems; idx += 512) {
      const int node = start + (idx >> 7);
      const int d = idx & 127;
      e[node * EP + d] += e[(2 * node + 1) * EP + d] + e[(2 * node + 2) * EP + d];
    }
    __syncthreads();
  }
  // per-dim max over all 127 nodes
  {
    const int d = t & 127;
    const int grp = t >> 7;  // 0..3
    float m = -1e30f;
    for (int r = grp; r < NPT; r += 4) m = fmaxf(m, e[r * EP + d]);
    pmax[grp][d] = m;
  }
  __syncthreads();
  if (t < 128) {
    float m = fmaxf(fmaxf(pmax[0][t], pmax[1][t]), fmaxf(pmax[2][t], pmax[3][t]));
    enc[(size_t)row * D + t] = fmaxf(m, 0.0f);
  }
}

// ---------------------------------------------------------------------------
// K1b: q/k/v projection GEMM. enc(4096x128) @ W(128x128) for Wq/Wk/Wv.
// ---------------------------------------------------------------------------
__global__ __launch_bounds__(256) void k1b_qkv(
    const float* __restrict__ enc, const float* __restrict__ Wq,
    const float* __restrict__ Wk, const float* __restrict__ Wv,
    float* __restrict__ qb, float* __restrict__ kb, float* __restrict__ vb) {
  __shared__ float sE[32 * D];  // 16 KB
  const int t = threadIdx.x;
  const int rb = blockIdx.x / 3;
  const int cb = blockIdx.x % 3;
  const int r0 = rb * 32;
  const float* W = cb == 0 ? Wq : (cb == 1 ? Wk : Wv);
  float* outb = cb == 0 ? qb : (cb == 1 ? kb : vb);
  {
    const float4* E4 = (const float4*)(enc + (size_t)r0 * D);
    float4* sE4 = (float4*)sE;
#pragma unroll
    for (int i = 0; i < 4; ++i) sE4[t + 256 * i] = E4[t + 256 * i];
  }
  __syncthreads();
  const int rg = t >> 5;
  const int cg = t & 31;
  float acc[4][4] = {};
#pragma unroll 4
  for (int k = 0; k < D; ++k) {
    float4 w = *(const float4*)&W[k * D + cg * 4];
    float e0 = sE[(rg * 4 + 0) * D + k];
    float e1 = sE[(rg * 4 + 1) * D + k];
    float e2 = sE[(rg * 4 + 2) * D + k];
    float e3 = sE[(rg * 4 + 3) * D + k];
    acc[0][0] += e0 * w.x; acc[0][1] += e0 * w.y; acc[0][2] += e0 * w.z; acc[0][3] += e0 * w.w;
    acc[1][0] += e1 * w.x; acc[1][1] += e1 * w.y; acc[1][2] += e1 * w.z; acc[1][3] += e1 * w.w;
    acc[2][0] += e2 * w.x; acc[2][1] += e2 * w.y; acc[2][2] += e2 * w.z; acc[2][3] += e2 * w.w;
    acc[3][0] += e3 * w.x; acc[3][1] += e3 * w.y; acc[3][2] += e3 * w.z; acc[3][3] += e3 * w.w;
  }
#pragma unroll
  for (int i = 0; i < 4; ++i) {
    float4 o = make_float4(acc[i][0], acc[i][1], acc[i][2], acc[i][3]);
    *(float4*)&outb[(size_t)(r0 + rg * 4 + i) * D + cg * 4] = o;
  }
}

// ---------------------------------------------------------------------------
// K2: attention for one (batch, split of 16 q-rows). Writes pre-Wo rows.
// ---------------------------------------------------------------------------
__global__ __launch_bounds__(512) void k2_attn(
    const float* __restrict__ qb, const float* __restrict__ kb,
    const float* __restrict__ vb, const int* __restrict__ mask,
    float* __restrict__ ob) {
  __shared__ float sK[L * KP];
  __shared__ float sV[L * KP];
  __shared__ float sQ[8][D];
  const int t = threadIdx.x;
  const int w = t >> 6, lane = t & 63;
  const int b = blockIdx.x / SPLIT;
  const int sp = blockIdx.x % SPLIT;
  for (int i = t * 4; i < L * D; i += 512 * 4) {
    int r = i >> 7, c = i & 127;
    float4 kv = *(const float4*)&kb[(size_t)(b * L + r) * D + c];
    float4 vv = *(const float4*)&vb[(size_t)(b * L + r) * D + c];
    sK[r * KP + c] = kv.x; sK[r * KP + c + 1] = kv.y;
    sK[r * KP + c + 2] = kv.z; sK[r * KP + c + 3] = kv.w;
    sV[r * KP + c] = vv.x; sV[r * KP + c + 1] = vv.y;
    sV[r * KP + c + 2] = vv.z; sV[r * KP + c + 3] = vv.w;
  }
  __syncthreads();
#pragma unroll
  for (int it = 0; it < 2; ++it) {
    const int r = sp * 16 + w * 2 + it;
    float2 qv = *(const float2*)&qb[(size_t)(b * L + r) * D + lane * 2];
    sQ[w][lane * 2] = qv.x;
    sQ[w][lane * 2 + 1] = qv.y;
    float sc = 0.f;
#pragma unroll 8
    for (int k = 0; k < D; ++k) sc += sQ[w][k] * sK[lane * KP + k];
    sc *= 0.08838834764831845f;
    if (mask[((size_t)b * L + r) * L + lane] <= 0) sc = -1e9f;
    float mx = sc;
#pragma unroll
    for (int off = 32; off >= 1; off >>= 1) mx = fmaxf(mx, __shfl_xor(mx, off));
    float ex = __expf(sc - mx);
    float sm = ex;
#pragma unroll
    for (int off = 32; off >= 1; off >>= 1) sm += __shfl_xor(sm, off);
    float a = ex / sm;
    float o0 = 0.f, o1 = 0.f;
#pragma unroll
    for (int j = 0; j < L; ++j) {
      float aj = __shfl(a, j);
      o0 += aj * sV[j * KP + lane];
      o1 += aj * sV[j * KP + lane + 64];
    }
    ob[(size_t)(b * L + r) * D + lane] = o0;
    ob[(size_t)(b * L + r) * D + lane + 64] = o1;
  }
}

// ---------------------------------------------------------------------------
// K23: per batch (64 blocks, 512 threads): out2 = ob@Wo in LDS,
// pooled max over rows, logits -> out.
// ---------------------------------------------------------------------------
__global__ __launch_bounds__(512) void k23_proj_pool(
    const float* __restrict__ ob, const float* __restrict__ Wo,
    const float* __restrict__ Wl, const float* __restrict__ bl,
    float* __restrict__ out) {
  __shared__ float sO[L * EP];    // 33.8 KB (ob tile, then out2 tile)
  __shared__ float pmax[4][D];
  __shared__ float sP[D];
  __shared__ float part[8][LABELS];
  const int t = threadIdx.x;
  const int b = blockIdx.x;
  for (int i = t * 4; i < L * D; i += 512 * 4) {
    int r = i >> 7, c = i & 127;
    float4 v = *(const float4*)&ob[(size_t)(b * L + r) * D + c];
    float* p = &sO[r * EP + c];
    p[0] = v.x; p[1] = v.y; p[2] = v.z; p[3] = v.w;
  }
  __syncthreads();
  const int rg = t >> 5;        // 0..15 -> 4 rows each
  const int cg = t & 31;        // 4 cols each
  const int r0 = rg * 4, c0 = cg * 4;
  float acc[4][4] = {};
#pragma unroll 4
  for (int k = 0; k < D; ++k) {
    float4 w = *(const float4*)&Wo[k * D + c0];
    float e0 = sO[(r0 + 0) * EP + k];
    float e1 = sO[(r0 + 1) * EP + k];
    float e2 = sO[(r0 + 2) * EP + k];
    float e3 = sO[(r0 + 3) * EP + k];
    acc[0][0] += e0 * w.x; acc[0][1] += e0 * w.y; acc[0][2] += e0 * w.z; acc[0][3] += e0 * w.w;
    acc[1][0] += e1 * w.x; acc[1][1] += e1 * w.y; acc[1][2] += e1 * w.z; acc[1][3] += e1 * w.w;
    acc[2][0] += e2 * w.x; acc[2][1] += e2 * w.y; acc[2][2] += e2 * w.z; acc[2][3] += e2 * w.w;
    acc[3][0] += e3 * w.x; acc[3][1] += e3 * w.y; acc[3][2] += e3 * w.z; acc[3][3] += e3 * w.w;
  }
  __syncthreads();  // all reads of ob tile done; overwrite with out2
#pragma unroll
  for (int i = 0; i < 4; ++i) {
    float4 o = make_float4(acc[i][0], acc[i][1], acc[i][2], acc[i][3]);
    *(float4*)&sO[(r0 + i) * EP + c0] = o;
  }
  __syncthreads();
  {
    const int d = t & 127;
    const int grp = t >> 7;
    float m = -1e30f;
    for (int r = grp; r < L; r += 4) m = fmaxf(m, sO[r * EP + d]);
    pmax[grp][d] = m;
  }
  __syncthreads();
  if (t < 128) {
    sP[t] = fmaxf(fmaxf(pmax[0][t], pmax[1][t]), fmaxf(pmax[2][t], pmax[3][t]));
  }
  __syncthreads();
  if (t < 8 * LABELS) {
    const int grp = t / LABELS;
    const int lab = t % LABELS;
    float a = 0.f;
#pragma unroll
    for (int j = 0; j < 16; ++j) {
      int d = grp * 16 + j;
      a += sP[d] * Wl[d * LABELS + lab];
    }
    part[grp][lab] = a;
  }
  __syncthreads();
  if (t < LABELS) {
    float a = bl[t];
#pragma unroll
    for (int g = 0; g < 8; ++g) a += part[g][t];
    out[b * LABELS + t] = a;
  }
}

extern "C" void kernel_launch(void* const* d_in, const int* in_sizes, int n_in,
                              void* d_out, int out_size, void* d_ws, size_t ws_size,
                              hipStream_t stream) {
  const int* tokens = (const int*)d_in[0];
  const int* mask = (const int*)d_in[1];
  const float* emb = (const float*)d_in[2];
  const float* Wc = (const float*)d_in[3];
  const float* bc = (const float*)d_in[4];
  const float* Wq = (const float*)d_in[5];
  const float* Wk = (const float*)d_in[6];
  const float* Wv = (const float*)d_in[7];
  const float* Wo = (const float*)d_in[8];
  const float* Wl = (const float*)d_in[9];
  const float* bl = (const float*)d_in[10];
  float* out = (float*)d_out;

  __hip_bfloat16* T = (__hip_bfloat16*)d_ws;        // VOCAB*D bf16 = 7.68 MB
  float* enc = (float*)(T + (size_t)VOCAB * D);     // B*L*D f32
  float* qb = enc + (size_t)B * L * D;
  float* kb = qb + (size_t)B * L * D;
  float* vb = kb + (size_t)B * L * D;
  float* obuf = vb + (size_t)B * L * D;

  hipLaunchKernelGGL(k0_embWc, dim3((VOCAB + 31) / 32), dim3(256), 0, stream,
                     emb, Wc, bc, T);
  hipLaunchKernelGGL(k1a_tree, dim3(B * L), dim3(512), 0, stream,
                     tokens, T, enc);
  hipLaunchKernelGGL(k1b_qkv, dim3((B * L / 32) * 3), dim3(256), 0, stream,
                     enc, Wq, Wk, Wv, qb, kb, vb);
  hipLaunchKernelGGL(k2_attn, dim3(B * SPLIT), dim3(512), 0, stream,
                     qb, kb, vb, mask, obuf);
  hipLaunchKernelGGL(k23_proj_pool, dim3(B), dim3(512), 0, stream,
                     obuf, Wo, Wl, bl, out);
}

// Round 5
// 85.211 us; speedup vs baseline: 1.3526x; 1.3526x over previous
//
#include <hip/hip_runtime.h>
#include <hip/hip_bf16.h>
#include <math.h>

#define B 64
#define L 64
#define NPT 127
#define D 128
#define VOCAB 30000
#define LABELS 30
#define SPLIT 4
#define KP 129    // padded LDS row stride (floats) for K/V tiles in k2
#define EP 132    // padded row stride for k23 tile

typedef __attribute__((ext_vector_type(4))) unsigned int uint4v;

__device__ __forceinline__ float bfhi(unsigned int u) {
  unsigned int x = u & 0xffff0000u;
  return __builtin_bit_cast(float, x);
}
__device__ __forceinline__ float bflo(unsigned int u) {
  unsigned int x = u << 16;
  return __builtin_bit_cast(float, x);
}

// ---------------------------------------------------------------------------
// K0: T[v][e] = bf16( sum_d emb[v][d] * Wc[d][e] + bc[e] )   (bc folded in)
// ---------------------------------------------------------------------------
__global__ __launch_bounds__(256) void k0_embWc(const float* __restrict__ emb,
                                                const float* __restrict__ Wc,
                                                const float* __restrict__ bc,
                                                __hip_bfloat16* __restrict__ T) {
  __shared__ float sW[D * D];  // 64 KB
  const int t = threadIdx.x;
  const int row0 = blockIdx.x * 32;
  {
    const float4* W4 = (const float4*)Wc;
    float4* sW4 = (float4*)sW;
#pragma unroll
    for (int i = 0; i < 16; ++i) sW4[t + 256 * i] = W4[t + 256 * i];
  }
  __syncthreads();
  const int rg = t >> 5;   // 0..7
  const int cg = t & 31;   // 0..31
  const int c0 = cg * 4;
  int rr[4];
#pragma unroll
  for (int i = 0; i < 4; ++i) {
    int g = row0 + rg * 4 + i;
    rr[i] = g < VOCAB ? g : VOCAB - 1;
  }
  const float4* e0 = (const float4*)(emb + (size_t)rr[0] * D);
  const float4* e1 = (const float4*)(emb + (size_t)rr[1] * D);
  const float4* e2 = (const float4*)(emb + (size_t)rr[2] * D);
  const float4* e3 = (const float4*)(emb + (size_t)rr[3] * D);
  const float4* sW4 = (const float4*)sW;
  float4 bcv = *(const float4*)&bc[c0];
  float acc[4][4];
#pragma unroll
  for (int i = 0; i < 4; ++i) {
    acc[i][0] = bcv.x; acc[i][1] = bcv.y; acc[i][2] = bcv.z; acc[i][3] = bcv.w;
  }
#pragma unroll 4
  for (int k4 = 0; k4 < 32; ++k4) {
    float4 a0 = e0[k4], a1 = e1[k4], a2 = e2[k4], a3 = e3[k4];
    const float av0[4] = {a0.x, a0.y, a0.z, a0.w};
    const float av1[4] = {a1.x, a1.y, a1.z, a1.w};
    const float av2[4] = {a2.x, a2.y, a2.z, a2.w};
    const float av3[4] = {a3.x, a3.y, a3.z, a3.w};
#pragma unroll
    for (int j = 0; j < 4; ++j) {
      float4 w = sW4[(k4 * 4 + j) * 32 + cg];
      float b0 = av0[j], b1 = av1[j], b2 = av2[j], b3 = av3[j];
      acc[0][0] += b0 * w.x; acc[0][1] += b0 * w.y; acc[0][2] += b0 * w.z; acc[0][3] += b0 * w.w;
      acc[1][0] += b1 * w.x; acc[1][1] += b1 * w.y; acc[1][2] += b1 * w.z; acc[1][3] += b1 * w.w;
      acc[2][0] += b2 * w.x; acc[2][1] += b2 * w.y; acc[2][2] += b2 * w.z; acc[2][3] += b2 * w.w;
      acc[3][0] += b3 * w.x; acc[3][1] += b3 * w.y; acc[3][2] += b3 * w.z; acc[3][3] += b3 * w.w;
    }
  }
  union BF4 { ushort4 u; unsigned short s[4]; };
#pragma unroll
  for (int i = 0; i < 4; ++i) {
    int g = row0 + rg * 4 + i;
    if (g < VOCAB) {
      BF4 o;
#pragma unroll
      for (int j = 0; j < 4; ++j) {
        __hip_bfloat16 h = __float2bfloat16(acc[i][j]);
        o.s[j] = *(unsigned short*)&h;
      }
      *(ushort4*)&T[(size_t)g * D + c0] = o.u;
    }
  }
}

// ---------------------------------------------------------------------------
// K1a: tree-encode, one WAVE per (b,l) row; 8 rows per 512-thread block.
// Lane l owns dims (2l, 2l+1); each node = one coalesced global_load_dword
// from L2-resident T (wave reads exactly one 256B row). Post-order streaming
// subtree-sum in a 6-deep register stack; running max; relu -> enc.
// No barriers, ~4KB LDS, no LDS round-trip for node data.
// ---------------------------------------------------------------------------
__global__ __launch_bounds__(512) void k1a_tree(
    const int* __restrict__ tokens, const __hip_bfloat16* __restrict__ T,
    float* __restrict__ enc) {
  __shared__ int stok[8][NPT];
  const int t = threadIdx.x;
  const int w = t >> 6;      // wave id = row within block
  const int lane = t & 63;
  const int row = blockIdx.x * 8 + w;
  const int base = row * NPT;
  // wave loads its own token row (wave-private LDS; in-wave lgkm ordering)
  stok[w][lane] = tokens[base + lane];
  if (lane < NPT - 64) stok[w][64 + lane] = tokens[base + 64 + lane];
  const unsigned short* Tp = (const unsigned short*)T;
  const unsigned off = lane * 2;  // ushort offset within row
  float m0 = -1e30f, m1 = -1e30f;
  float stk0[6], stk1[6];
#pragma unroll
  for (int li = 0; li < 64; ++li) {
    int tokl = __builtin_amdgcn_readfirstlane(stok[w][63 + li]);
    unsigned u = *(const unsigned*)(Tp + (size_t)tokl * D + off);
    float cur0 = bflo(u), cur1 = bfhi(u);
    m0 = fmaxf(m0, cur0);
    m1 = fmaxf(m1, cur1);
    int x = li;
#pragma unroll
    for (int h = 0; h < 6; ++h) {
      if (!(x & 1)) break;
      int pn = ((64 + li) >> (h + 1)) - 1;
      int tokp = __builtin_amdgcn_readfirstlane(stok[w][pn]);
      unsigned up = *(const unsigned*)(Tp + (size_t)tokp * D + off);
      cur0 = stk0[h] + cur0 + bflo(up);
      cur1 = stk1[h] + cur1 + bfhi(up);
      m0 = fmaxf(m0, cur0);
      m1 = fmaxf(m1, cur1);
      x >>= 1;
    }
    if (li != 63) {
      int h2 = 0, y = li;
      while (y & 1) { ++h2; y >>= 1; }
      stk0[h2] = cur0;
      stk1[h2] = cur1;
    }
  }
  float2 o = make_float2(fmaxf(m0, 0.0f), fmaxf(m1, 0.0f));
  *(float2*)&enc[(size_t)row * D + 2 * lane] = o;
}

// ---------------------------------------------------------------------------
// K1b: q/k/v projection GEMM. enc(4096x128) @ W(128x128) for Wq/Wk/Wv.
// ---------------------------------------------------------------------------
__global__ __launch_bounds__(256) void k1b_qkv(
    const float* __restrict__ enc, const float* __restrict__ Wq,
    const float* __restrict__ Wk, const float* __restrict__ Wv,
    float* __restrict__ qb, float* __restrict__ kb, float* __restrict__ vb) {
  __shared__ float sE[32 * D];  // 16 KB
  const int t = threadIdx.x;
  const int rb = blockIdx.x / 3;
  const int cb = blockIdx.x % 3;
  const int r0 = rb * 32;
  const float* W = cb == 0 ? Wq : (cb == 1 ? Wk : Wv);
  float* outb = cb == 0 ? qb : (cb == 1 ? kb : vb);
  {
    const float4* E4 = (const float4*)(enc + (size_t)r0 * D);
    float4* sE4 = (float4*)sE;
#pragma unroll
    for (int i = 0; i < 4; ++i) sE4[t + 256 * i] = E4[t + 256 * i];
  }
  __syncthreads();
  const int rg = t >> 5;
  const int cg = t & 31;
  float acc[4][4] = {};
#pragma unroll 4
  for (int k = 0; k < D; ++k) {
    float4 w = *(const float4*)&W[k * D + cg * 4];
    float e0 = sE[(rg * 4 + 0) * D + k];
    float e1 = sE[(rg * 4 + 1) * D + k];
    float e2 = sE[(rg * 4 + 2) * D + k];
    float e3 = sE[(rg * 4 + 3) * D + k];
    acc[0][0] += e0 * w.x; acc[0][1] += e0 * w.y; acc[0][2] += e0 * w.z; acc[0][3] += e0 * w.w;
    acc[1][0] += e1 * w.x; acc[1][1] += e1 * w.y; acc[1][2] += e1 * w.z; acc[1][3] += e1 * w.w;
    acc[2][0] += e2 * w.x; acc[2][1] += e2 * w.y; acc[2][2] += e2 * w.z; acc[2][3] += e2 * w.w;
    acc[3][0] += e3 * w.x; acc[3][1] += e3 * w.y; acc[3][2] += e3 * w.z; acc[3][3] += e3 * w.w;
  }
#pragma unroll
  for (int i = 0; i < 4; ++i) {
    float4 o = make_float4(acc[i][0], acc[i][1], acc[i][2], acc[i][3]);
    *(float4*)&outb[(size_t)(r0 + rg * 4 + i) * D + cg * 4] = o;
  }
}

// ---------------------------------------------------------------------------
// K2: attention for one (batch, split of 16 q-rows). Writes pre-Wo rows.
// ---------------------------------------------------------------------------
__global__ __launch_bounds__(512) void k2_attn(
    const float* __restrict__ qb, const float* __restrict__ kb,
    const float* __restrict__ vb, const int* __restrict__ mask,
    float* __restrict__ ob) {
  __shared__ float sK[L * KP];
  __shared__ float sV[L * KP];
  __shared__ float sQ[8][D];
  const int t = threadIdx.x;
  const int w = t >> 6, lane = t & 63;
  const int b = blockIdx.x / SPLIT;
  const int sp = blockIdx.x % SPLIT;
  for (int i = t * 4; i < L * D; i += 512 * 4) {
    int r = i >> 7, c = i & 127;
    float4 kv = *(const float4*)&kb[(size_t)(b * L + r) * D + c];
    float4 vv = *(const float4*)&vb[(size_t)(b * L + r) * D + c];
    sK[r * KP + c] = kv.x; sK[r * KP + c + 1] = kv.y;
    sK[r * KP + c + 2] = kv.z; sK[r * KP + c + 3] = kv.w;
    sV[r * KP + c] = vv.x; sV[r * KP + c + 1] = vv.y;
    sV[r * KP + c + 2] = vv.z; sV[r * KP + c + 3] = vv.w;
  }
  __syncthreads();
#pragma unroll
  for (int it = 0; it < 2; ++it) {
    const int r = sp * 16 + w * 2 + it;
    float2 qv = *(const float2*)&qb[(size_t)(b * L + r) * D + lane * 2];
    sQ[w][lane * 2] = qv.x;
    sQ[w][lane * 2 + 1] = qv.y;
    float sc = 0.f;
#pragma unroll 8
    for (int k = 0; k < D; ++k) sc += sQ[w][k] * sK[lane * KP + k];
    sc *= 0.08838834764831845f;
    if (mask[((size_t)b * L + r) * L + lane] <= 0) sc = -1e9f;
    float mx = sc;
#pragma unroll
    for (int off = 32; off >= 1; off >>= 1) mx = fmaxf(mx, __shfl_xor(mx, off));
    float ex = __expf(sc - mx);
    float sm = ex;
#pragma unroll
    for (int off = 32; off >= 1; off >>= 1) sm += __shfl_xor(sm, off);
    float a = ex / sm;
    float o0 = 0.f, o1 = 0.f;
#pragma unroll
    for (int j = 0; j < L; ++j) {
      float aj = __shfl(a, j);
      o0 += aj * sV[j * KP + lane];
      o1 += aj * sV[j * KP + lane + 64];
    }
    ob[(size_t)(b * L + r) * D + lane] = o0;
    ob[(size_t)(b * L + r) * D + lane + 64] = o1;
  }
}

// ---------------------------------------------------------------------------
// K23: per batch (64 blocks, 512 threads): out2 = ob@Wo in LDS,
// pooled max over rows, logits -> out.
// ---------------------------------------------------------------------------
__global__ __launch_bounds__(512) void k23_proj_pool(
    const float* __restrict__ ob, const float* __restrict__ Wo,
    const float* __restrict__ Wl, const float* __restrict__ bl,
    float* __restrict__ out) {
  __shared__ float sO[L * EP];
  __shared__ float pmax[4][D];
  __shared__ float sP[D];
  __shared__ float part[8][LABELS];
  const int t = threadIdx.x;
  const int b = blockIdx.x;
  for (int i = t * 4; i < L * D; i += 512 * 4) {
    int r = i >> 7, c = i & 127;
    float4 v = *(const float4*)&ob[(size_t)(b * L + r) * D + c];
    float* p = &sO[r * EP + c];
    p[0] = v.x; p[1] = v.y; p[2] = v.z; p[3] = v.w;
  }
  __syncthreads();
  const int rg = t >> 5;
  const int cg = t & 31;
  const int r0 = rg * 4, c0 = cg * 4;
  float acc[4][4] = {};
#pragma unroll 4
  for (int k = 0; k < D; ++k) {
    float4 w = *(const float4*)&Wo[k * D + c0];
    float e0 = sO[(r0 + 0) * EP + k];
    float e1 = sO[(r0 + 1) * EP + k];
    float e2 = sO[(r0 + 2) * EP + k];
    float e3 = sO[(r0 + 3) * EP + k];
    acc[0][0] += e0 * w.x; acc[0][1] += e0 * w.y; acc[0][2] += e0 * w.z; acc[0][3] += e0 * w.w;
    acc[1][0] += e1 * w.x; acc[1][1] += e1 * w.y; acc[1][2] += e1 * w.z; acc[1][3] += e1 * w.w;
    acc[2][0] += e2 * w.x; acc[2][1] += e2 * w.y; acc[2][2] += e2 * w.z; acc[2][3] += e2 * w.w;
    acc[3][0] += e3 * w.x; acc[3][1] += e3 * w.y; acc[3][2] += e3 * w.z; acc[3][3] += e3 * w.w;
  }
  __syncthreads();
#pragma unroll
  for (int i = 0; i < 4; ++i) {
    float4 o = make_float4(acc[i][0], acc[i][1], acc[i][2], acc[i][3]);
    *(float4*)&sO[(r0 + i) * EP + c0] = o;
  }
  __syncthreads();
  {
    const int d = t & 127;
    const int grp = t >> 7;
    float m = -1e30f;
    for (int r = grp; r < L; r += 4) m = fmaxf(m, sO[r * EP + d]);
    pmax[grp][d] = m;
  }
  __syncthreads();
  if (t < 128) {
    sP[t] = fmaxf(fmaxf(pmax[0][t], pmax[1][t]), fmaxf(pmax[2][t], pmax[3][t]));
  }
  __syncthreads();
  if (t < 8 * LABELS) {
    const int grp = t / LABELS;
    const int lab = t % LABELS;
    float a = 0.f;
#pragma unroll
    for (int j = 0; j < 16; ++j) {
      int d = grp * 16 + j;
      a += sP[d] * Wl[d * LABELS + lab];
    }
    part[grp][lab] = a;
  }
  __syncthreads();
  if (t < LABELS) {
    float a = bl[t];
#pragma unroll
    for (int g = 0; g < 8; ++g) a += part[g][t];
    out[b * LABELS + t] = a;
  }
}

extern "C" void kernel_launch(void* const* d_in, const int* in_sizes, int n_in,
                              void* d_out, int out_size, void* d_ws, size_t ws_size,
                              hipStream_t stream) {
  const int* tokens = (const int*)d_in[0];
  const int* mask = (const int*)d_in[1];
  const float* emb = (const float*)d_in[2];
  const float* Wc = (const float*)d_in[3];
  const float* bc = (const float*)d_in[4];
  const float* Wq = (const float*)d_in[5];
  const float* Wk = (const float*)d_in[6];
  const float* Wv = (const float*)d_in[7];
  const float* Wo = (const float*)d_in[8];
  const float* Wl = (const float*)d_in[9];
  const float* bl = (const float*)d_in[10];
  float* out = (float*)d_out;

  __hip_bfloat16* T = (__hip_bfloat16*)d_ws;        // VOCAB*D bf16 = 7.68 MB
  float* enc = (float*)(T + (size_t)VOCAB * D);     // B*L*D f32
  float* qb = enc + (size_t)B * L * D;
  float* kb = qb + (size_t)B * L * D;
  float* vb = kb + (size_t)B * L * D;
  float* obuf = vb + (size_t)B * L * D;

  hipLaunchKernelGGL(k0_embWc, dim3((VOCAB + 31) / 32), dim3(256), 0, stream,
                     emb, Wc, bc, T);
  hipLaunchKernelGGL(k1a_tree, dim3(B * L / 8), dim3(512), 0, stream,
                     tokens, T, enc);
  hipLaunchKernelGGL(k1b_qkv, dim3((B * L / 32) * 3), dim3(256), 0, stream,
                     enc, Wq, Wk, Wv, qb, kb, vb);
  hipLaunchKernelGGL(k2_attn, dim3(B * SPLIT), dim3(512), 0, stream,
                     qb, kb, vb, mask, obuf);
  hipLaunchKernelGGL(k23_proj_pool, dim3(B), dim3(512), 0, stream,
                     obuf, Wo, Wl, bl, out);
}

// Round 6
// 84.094 us; speedup vs baseline: 1.3705x; 1.0133x over previous
//
#include <hip/hip_runtime.h>
#include <hip/hip_bf16.h>
#include <math.h>

#define B 64
#define L 64
#define NPT 127
#define D 128
#define VOCAB 30000
#define LABELS 30
#define SPLIT 4
#define KP 132    // padded LDS row stride (floats) for K/V tiles in k2 (16B-aligned)
#define EP 132    // padded row stride for k23 tile
#define WCS 136   // wcT row stride in ushorts (272B: 16B-aligned)

typedef __attribute__((ext_vector_type(8))) short bf16x8;
typedef __attribute__((ext_vector_type(4))) float f32x4;

__device__ __forceinline__ float bfhi(unsigned int u) {
  unsigned int x = u & 0xffff0000u;
  return __builtin_bit_cast(float, x);
}
__device__ __forceinline__ float bflo(unsigned int u) {
  unsigned int x = u << 16;
  return __builtin_bit_cast(float, x);
}
__device__ __forceinline__ unsigned short f2bf(float f) {
  __hip_bfloat16 h = __float2bfloat16(f);  // RNE
  return __builtin_bit_cast(unsigned short, h);
}

// ---------------------------------------------------------------------------
// K0 (MFMA): T[v][e] = bf16( sum_d emb[v][d]*Wc[d][e] + bc[e] )
// Block: 256 thr = 4 waves; wave computes 16 rows x 128 cols via
// mfma_f32_16x16x32_bf16 (8 col-tiles x 4 k-chunks). Wc^T staged in LDS bf16.
// Layouts (m89-verified): A row=lane&15,k=(lane>>4)*8+j; B col=lane&15;
// C/D col=lane&15,row=(lane>>4)*4+reg.
// ---------------------------------------------------------------------------
__global__ __launch_bounds__(256) void k0_embWc(const float* __restrict__ emb,
                                                const float* __restrict__ Wc,
                                                const float* __restrict__ bc,
                                                __hip_bfloat16* __restrict__ T) {
  __shared__ unsigned short wcT[D * WCS];  // Wc^T bf16: wcT[e*WCS + d], ~34KB
  const int t = threadIdx.x;
  // stage transposed: lanes sweep d (contiguous LDS writes; strided global
  // reads hit L1-cached 64B lines reused across e iterations)
  for (int i = t; i < D * D; i += 256) {
    const int e = i >> 7, d = i & 127;
    wcT[e * WCS + d] = f2bf(Wc[d * D + e]);
  }
  __syncthreads();
  const int w = t >> 6, lane = t & 63;
  const int m = lane & 15;       // A-row / B-col within tile
  const int kg = lane >> 4;      // k-group 0..3
  int arow = blockIdx.x * 64 + w * 16 + m;
  if (arow >= VOCAB) arow = VOCAB - 1;  // clamp reads; stores guarded below
  const float* ap = emb + (size_t)arow * D + kg * 8;
  bf16x8 afrag[4];
#pragma unroll
  for (int kc = 0; kc < 4; ++kc) {
    float4 lo = *(const float4*)(ap + kc * 32);
    float4 hi = *(const float4*)(ap + kc * 32 + 4);
    union { bf16x8 v; unsigned short s[8]; } u;
    u.s[0] = f2bf(lo.x); u.s[1] = f2bf(lo.y); u.s[2] = f2bf(lo.z); u.s[3] = f2bf(lo.w);
    u.s[4] = f2bf(hi.x); u.s[5] = f2bf(hi.y); u.s[6] = f2bf(hi.z); u.s[7] = f2bf(hi.w);
    afrag[kc] = u.v;
  }
  const int grow0 = blockIdx.x * 64 + w * 16 + kg * 4;
#pragma unroll
  for (int ct = 0; ct < 8; ++ct) {
    const int col = ct * 16 + m;
    f32x4 acc = {0.f, 0.f, 0.f, 0.f};
#pragma unroll
    for (int kc = 0; kc < 4; ++kc) {
      bf16x8 bfrag = *(const bf16x8*)&wcT[col * WCS + kc * 32 + kg * 8];
      acc = __builtin_amdgcn_mfma_f32_16x16x32_bf16(afrag[kc], bfrag, acc, 0, 0, 0);
    }
    const float bcv = bc[col];
#pragma unroll
    for (int r = 0; r < 4; ++r) {
      const int grow = grow0 + r;
      if (grow < VOCAB)
        T[(size_t)grow * D + col] = __float2bfloat16(acc[r] + bcv);
    }
  }
}

// ---------------------------------------------------------------------------
// K1a: tree-encode, one WAVE per (b,l) row; 8 rows per 512-thread block.
// Lane l owns dims (2l, 2l+1); each node = one coalesced global_load_dword
// from L2-resident T. Post-order streaming subtree-sum in register stack.
// ---------------------------------------------------------------------------
__global__ __launch_bounds__(512) void k1a_tree(
    const int* __restrict__ tokens, const __hip_bfloat16* __restrict__ T,
    float* __restrict__ enc) {
  __shared__ int stok[8][NPT];
  const int t = threadIdx.x;
  const int w = t >> 6;
  const int lane = t & 63;
  const int row = blockIdx.x * 8 + w;
  const int base = row * NPT;
  stok[w][lane] = tokens[base + lane];
  if (lane < NPT - 64) stok[w][64 + lane] = tokens[base + 64 + lane];
  const unsigned short* Tp = (const unsigned short*)T;
  const unsigned off = lane * 2;
  float m0 = -1e30f, m1 = -1e30f;
  float stk0[6], stk1[6];
#pragma unroll
  for (int li = 0; li < 64; ++li) {
    int tokl = __builtin_amdgcn_readfirstlane(stok[w][63 + li]);
    unsigned u = *(const unsigned*)(Tp + (size_t)tokl * D + off);
    float cur0 = bflo(u), cur1 = bfhi(u);
    m0 = fmaxf(m0, cur0);
    m1 = fmaxf(m1, cur1);
    int x = li;
#pragma unroll
    for (int h = 0; h < 6; ++h) {
      if (!(x & 1)) break;
      int pn = ((64 + li) >> (h + 1)) - 1;
      int tokp = __builtin_amdgcn_readfirstlane(stok[w][pn]);
      unsigned up = *(const unsigned*)(Tp + (size_t)tokp * D + off);
      cur0 = stk0[h] + cur0 + bflo(up);
      cur1 = stk1[h] + cur1 + bfhi(up);
      m0 = fmaxf(m0, cur0);
      m1 = fmaxf(m1, cur1);
      x >>= 1;
    }
    if (li != 63) {
      int h2 = 0, y = li;
      while (y & 1) { ++h2; y >>= 1; }
      stk0[h2] = cur0;
      stk1[h2] = cur1;
    }
  }
  float2 o = make_float2(fmaxf(m0, 0.0f), fmaxf(m1, 0.0f));
  *(float2*)&enc[(size_t)row * D + 2 * lane] = o;
}

// ---------------------------------------------------------------------------
// K1b: q/k/v projection GEMM. enc(4096x128) @ W(128x128) for Wq/Wk/Wv.
// ---------------------------------------------------------------------------
__global__ __launch_bounds__(256) void k1b_qkv(
    const float* __restrict__ enc, const float* __restrict__ Wq,
    const float* __restrict__ Wk, const float* __restrict__ Wv,
    float* __restrict__ qb, float* __restrict__ kb, float* __restrict__ vb) {
  __shared__ float sE[32 * D];  // 16 KB
  const int t = threadIdx.x;
  const int rb = blockIdx.x / 3;
  const int cb = blockIdx.x % 3;
  const int r0 = rb * 32;
  const float* W = cb == 0 ? Wq : (cb == 1 ? Wk : Wv);
  float* outb = cb == 0 ? qb : (cb == 1 ? kb : vb);
  {
    const float4* E4 = (const float4*)(enc + (size_t)r0 * D);
    float4* sE4 = (float4*)sE;
#pragma unroll
    for (int i = 0; i < 4; ++i) sE4[t + 256 * i] = E4[t + 256 * i];
  }
  __syncthreads();
  const int rg = t >> 5;
  const int cg = t & 31;
  float acc[4][4] = {};
#pragma unroll 4
  for (int k = 0; k < D; ++k) {
    float4 w = *(const float4*)&W[k * D + cg * 4];
    float e0 = sE[(rg * 4 + 0) * D + k];
    float e1 = sE[(rg * 4 + 1) * D + k];
    float e2 = sE[(rg * 4 + 2) * D + k];
    float e3 = sE[(rg * 4 + 3) * D + k];
    acc[0][0] += e0 * w.x; acc[0][1] += e0 * w.y; acc[0][2] += e0 * w.z; acc[0][3] += e0 * w.w;
    acc[1][0] += e1 * w.x; acc[1][1] += e1 * w.y; acc[1][2] += e1 * w.z; acc[1][3] += e1 * w.w;
    acc[2][0] += e2 * w.x; acc[2][1] += e2 * w.y; acc[2][2] += e2 * w.z; acc[2][3] += e2 * w.w;
    acc[3][0] += e3 * w.x; acc[3][1] += e3 * w.y; acc[3][2] += e3 * w.z; acc[3][3] += e3 * w.w;
  }
#pragma unroll
  for (int i = 0; i < 4; ++i) {
    float4 o = make_float4(acc[i][0], acc[i][1], acc[i][2], acc[i][3]);
    *(float4*)&outb[(size_t)(r0 + rg * 4 + i) * D + cg * 4] = o;
  }
}

// ---------------------------------------------------------------------------
// K2: attention for one (batch, split of 16 q-rows). Writes pre-Wo rows.
// float4 score loop (KP=132 keeps 16B alignment; banks linear-equivalent).
// ---------------------------------------------------------------------------
__global__ __launch_bounds__(512) void k2_attn(
    const float* __restrict__ qb, const float* __restrict__ kb,
    const float* __restrict__ vb, const int* __restrict__ mask,
    float* __restrict__ ob) {
  __shared__ float sK[L * KP];
  __shared__ float sV[L * KP];
  __shared__ float sQ[8][D];
  const int t = threadIdx.x;
  const int w = t >> 6, lane = t & 63;
  const int b = blockIdx.x / SPLIT;
  const int sp = blockIdx.x % SPLIT;
  for (int i = t * 4; i < L * D; i += 512 * 4) {
    int r = i >> 7, c = i & 127;
    float4 kv = *(const float4*)&kb[(size_t)(b * L + r) * D + c];
    float4 vv = *(const float4*)&vb[(size_t)(b * L + r) * D + c];
    *(float4*)&sK[r * KP + c] = kv;
    *(float4*)&sV[r * KP + c] = vv;
  }
  __syncthreads();
#pragma unroll
  for (int it = 0; it < 2; ++it) {
    const int r = sp * 16 + w * 2 + it;
    float2 qv = *(const float2*)&qb[(size_t)(b * L + r) * D + lane * 2];
    sQ[w][lane * 2] = qv.x;
    sQ[w][lane * 2 + 1] = qv.y;
    float sc = 0.f;
    const float4* kr = (const float4*)&sK[lane * KP];
    const float4* qr = (const float4*)&sQ[w][0];
#pragma unroll 8
    for (int k4 = 0; k4 < 32; ++k4) {
      float4 kv = kr[k4];
      float4 q4 = qr[k4];
      sc += q4.x * kv.x + q4.y * kv.y + q4.z * kv.z + q4.w * kv.w;
    }
    sc *= 0.08838834764831845f;
    if (mask[((size_t)b * L + r) * L + lane] <= 0) sc = -1e9f;
    float mx = sc;
#pragma unroll
    for (int off = 32; off >= 1; off >>= 1) mx = fmaxf(mx, __shfl_xor(mx, off));
    float ex = __expf(sc - mx);
    float sm = ex;
#pragma unroll
    for (int off = 32; off >= 1; off >>= 1) sm += __shfl_xor(sm, off);
    float a = ex / sm;
    float o0 = 0.f, o1 = 0.f;
#pragma unroll
    for (int j = 0; j < L; ++j) {
      float aj = __shfl(a, j);
      o0 += aj * sV[j * KP + lane];
      o1 += aj * sV[j * KP + lane + 64];
    }
    ob[(size_t)(b * L + r) * D + lane] = o0;
    ob[(size_t)(b * L + r) * D + lane + 64] = o1;
  }
}

// ---------------------------------------------------------------------------
// K23: per batch (64 blocks, 512 threads): out2 = ob@Wo in LDS,
// pooled max over rows, logits -> out.
// ---------------------------------------------------------------------------
__global__ __launch_bounds__(512) void k23_proj_pool(
    const float* __restrict__ ob, const float* __restrict__ Wo,
    const float* __restrict__ Wl, const float* __restrict__ bl,
    float* __restrict__ out) {
  __shared__ float sO[L * EP];
  __shared__ float pmax[4][D];
  __shared__ float sP[D];
  __shared__ float part[8][LABELS];
  const int t = threadIdx.x;
  const int b = blockIdx.x;
  for (int i = t * 4; i < L * D; i += 512 * 4) {
    int r = i >> 7, c = i & 127;
    float4 v = *(const float4*)&ob[(size_t)(b * L + r) * D + c];
    float* p = &sO[r * EP + c];
    p[0] = v.x; p[1] = v.y; p[2] = v.z; p[3] = v.w;
  }
  __syncthreads();
  const int rg = t >> 5;
  const int cg = t & 31;
  const int r0 = rg * 4, c0 = cg * 4;
  float acc[4][4] = {};
#pragma unroll 4
  for (int k = 0; k < D; ++k) {
    float4 w = *(const float4*)&Wo[k * D + c0];
    float e0 = sO[(r0 + 0) * EP + k];
    float e1 = sO[(r0 + 1) * EP + k];
    float e2 = sO[(r0 + 2) * EP + k];
    float e3 = sO[(r0 + 3) * EP + k];
    acc[0][0] += e0 * w.x; acc[0][1] += e0 * w.y; acc[0][2] += e0 * w.z; acc[0][3] += e0 * w.w;
    acc[1][0] += e1 * w.x; acc[1][1] += e1 * w.y; acc[1][2] += e1 * w.z; acc[1][3] += e1 * w.w;
    acc[2][0] += e2 * w.x; acc[2][1] += e2 * w.y; acc[2][2] += e2 * w.z; acc[2][3] += e2 * w.w;
    acc[3][0] += e3 * w.x; acc[3][1] += e3 * w.y; acc[3][2] += e3 * w.z; acc[3][3] += e3 * w.w;
  }
  __syncthreads();
#pragma unroll
  for (int i = 0; i < 4; ++i) {
    float4 o = make_float4(acc[i][0], acc[i][1], acc[i][2], acc[i][3]);
    *(float4*)&sO[(r0 + i) * EP + c0] = o;
  }
  __syncthreads();
  {
    const int d = t & 127;
    const int grp = t >> 7;
    float m = -1e30f;
    for (int r = grp; r < L; r += 4) m = fmaxf(m, sO[r * EP + d]);
    pmax[grp][d] = m;
  }
  __syncthreads();
  if (t < 128) {
    sP[t] = fmaxf(fmaxf(pmax[0][t], pmax[1][t]), fmaxf(pmax[2][t], pmax[3][t]));
  }
  __syncthreads();
  if (t < 8 * LABELS) {
    const int grp = t / LABELS;
    const int lab = t % LABELS;
    float a = 0.f;
#pragma unroll
    for (int j = 0; j < 16; ++j) {
      int d = grp * 16 + j;
      a += sP[d] * Wl[d * LABELS + lab];
    }
    part[grp][lab] = a;
  }
  __syncthreads();
  if (t < LABELS) {
    float a = bl[t];
#pragma unroll
    for (int g = 0; g < 8; ++g) a += part[g][t];
    out[b * LABELS + t] = a;
  }
}

extern "C" void kernel_launch(void* const* d_in, const int* in_sizes, int n_in,
                              void* d_out, int out_size, void* d_ws, size_t ws_size,
                              hipStream_t stream) {
  const int* tokens = (const int*)d_in[0];
  const int* mask = (const int*)d_in[1];
  const float* emb = (const float*)d_in[2];
  const float* Wc = (const float*)d_in[3];
  const float* bc = (const float*)d_in[4];
  const float* Wq = (const float*)d_in[5];
  const float* Wk = (const float*)d_in[6];
  const float* Wv = (const float*)d_in[7];
  const float* Wo = (const float*)d_in[8];
  const float* Wl = (const float*)d_in[9];
  const float* bl = (const float*)d_in[10];
  float* out = (float*)d_out;

  __hip_bfloat16* T = (__hip_bfloat16*)d_ws;        // VOCAB*D bf16 = 7.68 MB
  float* enc = (float*)(T + (size_t)VOCAB * D);     // B*L*D f32
  float* qb = enc + (size_t)B * L * D;
  float* kb = qb + (size_t)B * L * D;
  float* vb = kb + (size_t)B * L * D;
  float* obuf = vb + (size_t)B * L * D;

  hipLaunchKernelGGL(k0_embWc, dim3((VOCAB + 63) / 64), dim3(256), 0, stream,
                     emb, Wc, bc, T);
  hipLaunchKernelGGL(k1a_tree, dim3(B * L / 8), dim3(512), 0, stream,
                     tokens, T, enc);
  hipLaunchKernelGGL(k1b_qkv, dim3((B * L / 32) * 3), dim3(256), 0, stream,
                     enc, Wq, Wk, Wv, qb, kb, vb);
  hipLaunchKernelGGL(k2_attn, dim3(B * SPLIT), dim3(512), 0, stream,
                     qb, kb, vb, mask, obuf);
  hipLaunchKernelGGL(k23_proj_pool, dim3(B), dim3(512), 0, stream,
                     obuf, Wo, Wl, bl, out);
}